// Round 5
// baseline (15.634 us; speedup 1.0000x reference)
//
#include <hip/hip_runtime.h>

// RoutingMaskLayer: in [B=64,H=32,W=32,C=512] f32, routing [B=64,4] f32.
// route[b]=argmax(routing[b,:]); out[b,h,w,c]=in[b,h,w, route[b]*128+c]
// Memory-bound gather. Round 4: nontemporal loads AND stores (both sides
// stream-once), 4 vecs/thread, grid 2048.

typedef float f32x4 __attribute__((ext_vector_type(4)));

constexpr int Bn     = 64;
constexpr int Hn     = 32;
constexpr int Wn     = 32;
constexpr int Cn     = 512;
constexpr int ROUTES = 4;
constexpr int RW     = Cn / ROUTES;       // 128 out channels / pixel
constexpr int VPP    = RW / 4;            // 32 f32x4 per pixel (out)
constexpr int TOTAL_VECS = Bn * Hn * Wn * VPP;      // 2,097,152
constexpr int VECS_PER_BLOCK = 1024;                 // 4 per thread * 256
constexpr int BLOCKS = TOTAL_VECS / VECS_PER_BLOCK;  // 2048
constexpr int BLOCKS_PER_IMG = (Hn * Wn * VPP) / VECS_PER_BLOCK;  // 32

__global__ __launch_bounds__(256)
void routing_gather_kernel(const f32x4* __restrict__ in,
                           const float* __restrict__ routing,
                           f32x4* __restrict__ out) {
    const int b = blockIdx.x >> 5;  // image index (32 blocks/image)

    // argmax over 4 routes (strict '>' = jnp.argmax first-max semantics).
    // Normal (cached) load — broadcast-shared across all blocks of the image.
    const f32x4 r = *reinterpret_cast<const f32x4*>(routing + b * ROUTES);
    int   best = 0;
    float bv   = r.x;
    if (r.y > bv) { bv = r.y; best = 1; }
    if (r.z > bv) { bv = r.z; best = 2; }
    if (r.w > bv) { bv = r.w; best = 3; }
    const int boff = best << 5;     // best * VPP

    const int base = blockIdx.x * VECS_PER_BLOCK + threadIdx.x;
    const int v0 = base;
    const int v1 = base + 256;
    const int v2 = base + 512;
    const int v3 = base + 768;

    // in vec index for out vec v: (pixel<<7) + best*32 + (v&31), pixel = v>>5
    const int i0 = ((v0 >> 5) << 7) + boff + (v0 & 31);
    const int i1 = ((v1 >> 5) << 7) + boff + (v1 & 31);
    const int i2 = ((v2 >> 5) << 7) + boff + (v2 & 31);
    const int i3 = ((v3 >> 5) << 7) + boff + (v3 & 31);

    // 4 independent streaming loads in flight, then 4 streaming stores.
    const f32x4 a0 = __builtin_nontemporal_load(&in[i0]);
    const f32x4 a1 = __builtin_nontemporal_load(&in[i1]);
    const f32x4 a2 = __builtin_nontemporal_load(&in[i2]);
    const f32x4 a3 = __builtin_nontemporal_load(&in[i3]);
    __builtin_nontemporal_store(a0, &out[v0]);
    __builtin_nontemporal_store(a1, &out[v1]);
    __builtin_nontemporal_store(a2, &out[v2]);
    __builtin_nontemporal_store(a3, &out[v3]);
}

extern "C" void kernel_launch(void* const* d_in, const int* in_sizes, int n_in,
                              void* d_out, int out_size, void* d_ws, size_t ws_size,
                              hipStream_t stream) {
    const f32x4* in      = (const f32x4*)d_in[0];
    const float* routing = (const float*)d_in[1];
    f32x4*       out     = (f32x4*)d_out;

    routing_gather_kernel<<<BLOCKS, 256, 0, stream>>>(in, routing, out);
}

// Round 6
// 14.997 us; speedup vs baseline: 1.0424x; 1.0424x over previous
//
#include <hip/hip_runtime.h>

// RoutingMaskLayer: in [B=64,H=32,W=32,C=512] f32, routing [B=64,4] f32.
// route[b]=argmax(routing[b,:]); out[b,h,w,c]=in[b,h,w, route[b]*128+c]
// Memory-bound gather. Round 6: max TLP — 1 vec/thread, 8192 blocks,
// NT stores (write-once output), cached loads (L3-resident input).

typedef float f32x4 __attribute__((ext_vector_type(4)));

constexpr int Bn     = 64;
constexpr int Hn     = 32;
constexpr int Wn     = 32;
constexpr int Cn     = 512;
constexpr int ROUTES = 4;
constexpr int RW     = Cn / ROUTES;       // 128 out channels / pixel
constexpr int VPP    = RW / 4;            // 32 f32x4 per pixel (out)
constexpr int TOTAL_VECS = Bn * Hn * Wn * VPP;      // 2,097,152
constexpr int BLOCKS = TOTAL_VECS / 256;             // 8192, 1 vec/thread
// 8192 blocks / 64 images = 128 blocks per image -> blockIdx>>7 = image

__global__ __launch_bounds__(256)
void routing_gather_kernel(const f32x4* __restrict__ in,
                           const float* __restrict__ routing,
                           f32x4* __restrict__ out) {
    const int b = blockIdx.x >> 7;  // image index (128 blocks/image)

    // argmax over 4 routes (strict '>' = jnp.argmax first-max semantics).
    // Cached load — broadcast-shared, L1/L3-resident.
    const f32x4 r = *reinterpret_cast<const f32x4*>(routing + b * ROUTES);
    int   best = 0;
    float bv   = r.x;
    if (r.y > bv) { bv = r.y; best = 1; }
    if (r.z > bv) { bv = r.z; best = 2; }
    if (r.w > bv) { bv = r.w; best = 3; }
    const int boff = best << 5;     // best * VPP

    const int v = blockIdx.x * 256 + threadIdx.x;
    // in vec index for out vec v: (pixel<<7) + best*32 + (v&31), pixel = v>>5
    const int i = ((v >> 5) << 7) + boff + (v & 31);

    const f32x4 a = in[i];
    __builtin_nontemporal_store(a, &out[v]);
}

extern "C" void kernel_launch(void* const* d_in, const int* in_sizes, int n_in,
                              void* d_out, int out_size, void* d_ws, size_t ws_size,
                              hipStream_t stream) {
    const f32x4* in      = (const f32x4*)d_in[0];
    const float* routing = (const float*)d_in[1];
    f32x4*       out     = (f32x4*)d_out;

    routing_gather_kernel<<<BLOCKS, 256, 0, stream>>>(in, routing, out);
}

// Round 7
// 14.093 us; speedup vs baseline: 1.1093x; 1.0641x over previous
//
#include <hip/hip_runtime.h>

// RoutingMaskLayer: in [B=64,H=32,W=32,C=512] f32, routing [B=64,4] f32.
// route[b]=argmax(routing[b,:]); out[b,h,w,c]=in[b,h,w, route[b]*128+c]
// Memory-bound gather. Round 7: revert to best measured config (R4):
// 2 vecs/thread, 4096 blocks, NT stores (write-once output skips L2),
// cached loads (L3-resident input). Grid-shape curve measured:
// 2048 blk=15.6-16.0us, 4096 blk=14.0us, 8192 blk=15.0us.

typedef float f32x4 __attribute__((ext_vector_type(4)));

constexpr int Bn     = 64;
constexpr int Hn     = 32;
constexpr int Wn     = 32;
constexpr int Cn     = 512;
constexpr int ROUTES = 4;
constexpr int RW     = Cn / ROUTES;       // 128 out channels / pixel
constexpr int VPP    = RW / 4;            // 32 f32x4 per pixel (out)
constexpr int TOTAL_VECS = Bn * Hn * Wn * VPP;      // 2,097,152
constexpr int VECS_PER_BLOCK = 512;                  // 2 per thread * 256
constexpr int BLOCKS = TOTAL_VECS / VECS_PER_BLOCK;  // 4096
// 4096 blocks / 64 images = 64 blocks per image -> blockIdx>>6 = image

__global__ __launch_bounds__(256)
void routing_gather_kernel(const f32x4* __restrict__ in,
                           const float* __restrict__ routing,
                           f32x4* __restrict__ out) {
    const int b = blockIdx.x >> 6;  // image index (64 blocks/image)

    // argmax over 4 routes (strict '>' = jnp.argmax first-max semantics).
    const f32x4 r = *reinterpret_cast<const f32x4*>(routing + b * ROUTES);
    int   best = 0;
    float bv   = r.x;
    if (r.y > bv) { bv = r.y; best = 1; }
    if (r.z > bv) { bv = r.z; best = 2; }
    if (r.w > bv) { bv = r.w; best = 3; }
    const int boff = best << 5;     // best * VPP

    const int base = blockIdx.x * VECS_PER_BLOCK + threadIdx.x;
    const int v0 = base;
    const int v1 = base + 256;

    // in vec index for out vec v: (pixel<<7) + best*32 + (v&31), pixel = v>>5
    const int i0 = ((v0 >> 5) << 7) + boff + (v0 & 31);
    const int i1 = ((v1 >> 5) << 7) + boff + (v1 & 31);

    const f32x4 a0 = in[i0];
    const f32x4 a1 = in[i1];
    __builtin_nontemporal_store(a0, &out[v0]);
    __builtin_nontemporal_store(a1, &out[v1]);
}

extern "C" void kernel_launch(void* const* d_in, const int* in_sizes, int n_in,
                              void* d_out, int out_size, void* d_ws, size_t ws_size,
                              hipStream_t stream) {
    const f32x4* in      = (const f32x4*)d_in[0];
    const float* routing = (const float*)d_in[1];
    f32x4*       out     = (f32x4*)d_out;

    routing_gather_kernel<<<BLOCKS, 256, 0, stream>>>(in, routing, out);
}